// Round 11
// baseline (126.538 us; speedup 1.0000x reference)
//
#include <hip/hip_runtime.h>
#include <hip/hip_bf16.h>

// Fused 34->128->128->1 MLP, bf16 MFMA, transposed GEMMs.
// R11 = R10 + 2-BARRIER PIPELINED TILE + PART stride 65.
//  - A0 double-buffered (+9KB LDS): tile t+1 is staged MID-tile-t (gathers
//    issue right after L0 using prefetched feB; consumed before B2). The
//    per-tile staging barrier disappears: 3 -> 2 __syncthreads per tile,
//    and gather latency hides under epi0/L1 instead of sitting on the
//    critical path. Gather regs live only across epi0 (~30 instrs) - the
//    R8 spill came from cross-MFMA liveness, avoided here.
//  - PART[16][65]: old stride 64 put the 4 q-lanes of each (pb,cl) on one
//    bank -> 4-way conflict on every PART write; 65 staggers them.
// R10 recap (kept): rotated w1r kills own[] spill; R8a permuted hidden
// (epi0 16 b128, L1 48 b128, own-frag forwarded); R7 transposed GEMMs.
// Tripwire: WRITE_SIZE >> 4MB = spill (R3/R8/R9 lesson).

using bf16x8 = __attribute__((ext_vector_type(8))) short;   // 8 bf16 = 4 VGPRs
using f32x4  = __attribute__((ext_vector_type(4))) float;   // MFMA C/D

#define NPTS    1000000
#define NUMEMB  6572
#define HID     128
#define M_IT    64          // points per block-iteration
#define A0S     72          // A0 row stride in bf16 (144B, 16B-aligned rows)
#define H0S     136         // H0 row stride in bf16 (272B, 16B-aligned rows)
#define TILES   (NPTS / M_IT)   // 15625 exactly
#define NBLOCKS 768         // 3 blocks/CU on 256 CUs

__device__ __forceinline__ unsigned short bf16r(float f) {
    unsigned u;
    __builtin_memcpy(&u, &f, 4);
    u = (u + 0x7fffu + ((u >> 16) & 1u)) >> 16;
    return (unsigned short)u;
}
__device__ __forceinline__ unsigned pk2(float a, float b) {
    // packed RNE f32x2 -> bf16x2 (v_cvt_pk_bf16_f32 on gfx950)
    float2 f2; f2.x = a; f2.y = b;
    __hip_bfloat162 h = __float22bfloat162_rn(f2);
    unsigned u;
    __builtin_memcpy(&u, &h, 4);
    return u;
}
__device__ __forceinline__ float clamp01(float x) {
    return __builtin_amdgcn_fmed3f(x, 0.f, 1.f);
}

__global__ __launch_bounds__(256, 3)
void mlp_fused(const float* __restrict__ x,
               const float* __restrict__ emb,
               const float* __restrict__ em_table,
               const float* __restrict__ W0, const float* __restrict__ b0,
               const float* __restrict__ W1, const float* __restrict__ b1,
               const float* __restrict__ W2, const float* __restrict__ b2,
               float* __restrict__ out)
{
    __shared__ __align__(16) unsigned short A0[2 * M_IT * A0S]; // dbuf [pt][in]
    __shared__ __align__(16) unsigned short H0[M_IT * H0S];     // [pt][hperm]
    __shared__ __align__(16) float PART[16][65];                // [nq*4+q][pt]

    const int tid  = threadIdx.x;
    const int lane = tid & 63;
    const int nq   = tid >> 6;   // wave's physical hidden block [nq*32,+32)
    const int q    = lane >> 4;  // quad within wave
    const int cl   = lane & 15;
    const int p    = tid >> 2;   // staging: point within tile
    const int s    = tid & 3;    // staging: 8-dim segment of embedding

    // zero both A0 buffers once (cols 34..71 stay zero forever)
    for (int i = tid; i < 2 * M_IT * A0S; i += 256) A0[i] = 0;

    // ---- one-time: weight A-fragments (permuted cols) into registers ----
    // A-frag lane (q,cl) holds A[m=cl][k=q*8+e]. Permuted physical hidden
    // for column m within block (nq,hb): h = nq*32 + (m>>2)*8 + hb*4 + (m&3).
    const int hcol = nq * 32 + (cl >> 2) * 8 + (cl & 3);  // + hb*4
    // W0 logical row k: k<32 -> em row 2+k ; k==32 -> x row 0 ; k==33 -> 1.
    bf16x8 w0t[2][2];   // [hb][kt]
    for (int hb = 0; hb < 2; ++hb)
        for (int kt = 0; kt < 2; ++kt) {
            const int col = hcol + hb * 4;
            bf16x8 v;
            #pragma unroll
            for (int e = 0; e < 8; ++e) {
                const int k = kt * 32 + q * 8 + e;
                float val = 0.f;
                if (k < 32)       val = W0[(2 + k) * HID + col];
                else if (k == 32) val = W0[0 * HID + col];
                else if (k == 33) val = W0[1 * HID + col];
                v[e] = (short)bf16r(val);
            }
            w0t[hb][kt] = v;
        }

    // W1 ROTATED: w1r[hb][kk] holds rows kphys = ((nq+kk)&3)*32 + q*8 + e;
    // kk=0 is the wave's own kt (consumes own[], which then dies).
    bf16x8 w1r[2][4];   // [hb][kk]
    for (int hb = 0; hb < 2; ++hb)
        for (int kk = 0; kk < 4; ++kk) {
            const int kt  = (nq + kk) & 3;
            const int col = hcol + hb * 4;
            bf16x8 v;
            #pragma unroll
            for (int e = 0; e < 8; ++e) {
                const int k = kt * 32 + q * 8 + e;
                v[e] = (short)bf16r(W1[k * HID + col]);
            }
            w1r[hb][kk] = v;
        }

    // biases / W2 indexed by this lane's physical h = nq*32 + q*8 + hb*4 + r
    f32x4 b0q[2], b1q[2], w2q[2];
    for (int hb = 0; hb < 2; ++hb)
        for (int r = 0; r < 4; ++r) {
            const int h = nq * 32 + q * 8 + hb * 4 + r;
            b0q[hb][r] = b0[h];
            b1q[hb][r] = b1[h];
            w2q[hb][r] = W2[h];
        }
    const float bias2 = b2[0];

    // ---- prologue: stage tile t0 into buf 0; prefetch fe/x for t0+grid ----
    int t = blockIdx.x;
    int cur = 0;
    {
        const int gp = t * M_IT + p;
        const float fe = emb[gp];
        float2 xv = {0.f, 0.f};
        if (s == 0) xv = *(const float2*)(x + 2 * gp);
        const int e1 = (int)fe;
        const int e2 = (e1 + 1 < NUMEMB) ? e1 + 1 : NUMEMB - 1;
        const float r = fe - (float)e1;
        const float4* p1 = (const float4*)(em_table + e1 * 32 + s * 8);
        const float4* p2 = (const float4*)(em_table + e2 * 32 + s * 8);
        const float4 g0 = p1[0], g1 = p1[1], g2 = p2[0], g3 = p2[1];
        uint4 d;
        d.x = pk2(g0.x + (g2.x - g0.x) * r, g0.y + (g2.y - g0.y) * r);
        d.y = pk2(g0.z + (g2.z - g0.z) * r, g0.w + (g2.w - g0.w) * r);
        d.z = pk2(g1.x + (g3.x - g1.x) * r, g1.y + (g3.y - g1.y) * r);
        d.w = pk2(g1.z + (g3.z - g1.z) * r, g1.w + (g3.w - g1.w) * r);
        *(uint4*)&A0[p * A0S + s * 8] = d;
        if (s == 0) *(unsigned*)&A0[p * A0S + 32] = pk2(xv.x, xv.y);
    }
    float  feB;
    float2 xvB = {0.f, 0.f};
    {
        int t1 = t + gridDim.x; if (t1 >= TILES) t1 = t;
        const int gp = t1 * M_IT + p;
        feB = emb[gp];
        if (s == 0) xvB = *(const float2*)(x + 2 * gp);
    }

    __syncthreads();   // A0 zero + first staging visible

    for (; t < TILES; t += gridDim.x, cur ^= 1) {
        const int base = t * M_IT;
        const unsigned short* A0c = A0 + cur * (M_IT * A0S);
        unsigned short*       A0n = A0 + (cur ^ 1) * (M_IT * A0S);

        // ---- layer 0 (transposed, permuted cols): bias in acc ----
        f32x4 acc[4][2];   // [pb][hb]
        #pragma unroll
        for (int pb = 0; pb < 4; ++pb)
            #pragma unroll
            for (int hb = 0; hb < 2; ++hb)
                acc[pb][hb] = b0q[hb];
        #pragma unroll
        for (int pb = 0; pb < 4; ++pb) {
            #pragma unroll
            for (int kt = 0; kt < 2; ++kt) {
                bf16x8 bfrag = *(const bf16x8*)
                    &A0c[(pb * 16 + cl) * A0S + kt * 32 + q * 8];
                #pragma unroll
                for (int hb = 0; hb < 2; ++hb)
                    acc[pb][hb] = __builtin_amdgcn_mfma_f32_16x16x32_bf16(
                        w0t[hb][kt], bfrag, acc[pb][hb], 0, 0, 0);
            }
        }

        // ---- issue gathers for tile t+1 (feB ready; short liveness) ----
        const int ge1 = (int)feB;
        const int ge2 = (ge1 + 1 < NUMEMB) ? ge1 + 1 : NUMEMB - 1;
        const float4* gp1 = (const float4*)(em_table + ge1 * 32 + s * 8);
        const float4* gp2 = (const float4*)(em_table + ge2 * 32 + s * 8);
        const float4 g0 = gp1[0], g1 = gp1[1], g2 = gp2[0], g3 = gp2[1];

        // epi0: lane's 8 permuted hiddens == L1 B-frag for kt=nq.
        // One b128 to H0 (for the other 3 waves) + keep in registers.
        uint4 own[4];
        #pragma unroll
        for (int pb = 0; pb < 4; ++pb) {
            const f32x4 v0 = acc[pb][0], v1 = acc[pb][1];
            uint4 w;
            w.x = pk2(clamp01(v0[0]), clamp01(v0[1]));
            w.y = pk2(clamp01(v0[2]), clamp01(v0[3]));
            w.z = pk2(clamp01(v1[0]), clamp01(v1[1]));
            w.w = pk2(clamp01(v1[2]), clamp01(v1[3]));
            own[pb] = w;
            *(uint4*)&H0[(pb * 16 + cl) * H0S + nq * 32 + q * 8] = w;
        }

        // ---- consume gathers: stage tile t+1 into A0n ----
        {
            const float r = feB - (float)ge1;
            uint4 d;
            d.x = pk2(g0.x + (g2.x - g0.x) * r, g0.y + (g2.y - g0.y) * r);
            d.y = pk2(g0.z + (g2.z - g0.z) * r, g0.w + (g2.w - g0.w) * r);
            d.z = pk2(g1.x + (g3.x - g1.x) * r, g1.y + (g3.y - g1.y) * r);
            d.w = pk2(g1.z + (g3.z - g1.z) * r, g1.w + (g3.w - g1.w) * r);
            *(uint4*)&A0n[p * A0S + s * 8] = d;
            if (s == 0) *(unsigned*)&A0n[p * A0S + 32] = pk2(xvB.x, xvB.y);
        }
        // prefetch fe/x for tile t+2 (3 regs live across L1 only)
        {
            int t2 = t + 2 * (int)gridDim.x; if (t2 >= TILES) t2 = t;
            const int gp = t2 * M_IT + p;
            feB = emb[gp];
            if (s == 0) xvB = *(const float2*)(x + 2 * gp);
        }
        __syncthreads();   // B2: H0 + A0n visible

        // ---- layer 1: kk=0 consumes own[] (then dead); kk>=1 from LDS ----
        #pragma unroll
        for (int pb = 0; pb < 4; ++pb)
            #pragma unroll
            for (int hb = 0; hb < 2; ++hb)
                acc[pb][hb] = b1q[hb];
        #pragma unroll
        for (int pb = 0; pb < 4; ++pb) {
            bf16x8 bfrag;
            __builtin_memcpy(&bfrag, &own[pb], 16);
            #pragma unroll
            for (int hb = 0; hb < 2; ++hb)
                acc[pb][hb] = __builtin_amdgcn_mfma_f32_16x16x32_bf16(
                    w1r[hb][0], bfrag, acc[pb][hb], 0, 0, 0);
        }
        #pragma unroll
        for (int kk = 1; kk < 4; ++kk) {
            const int kcol = (((nq + kk) & 3) << 5) + q * 8;  // runtime addr
            #pragma unroll
            for (int pb = 0; pb < 4; ++pb) {
                bf16x8 bfrag = *(const bf16x8*)
                    &H0[(pb * 16 + cl) * H0S + kcol];
                #pragma unroll
                for (int hb = 0; hb < 2; ++hb)
                    acc[pb][hb] = __builtin_amdgcn_mfma_f32_16x16x32_bf16(
                        w1r[hb][kk], bfrag, acc[pb][hb], 0, 0, 0);
            }
        }

        // ---- epi1 + layer 2: within-lane dot over lane's 8 physical h2 ----
        #pragma unroll
        for (int pb = 0; pb < 4; ++pb) {
            float sum = 0.f;
            #pragma unroll
            for (int hb = 0; hb < 2; ++hb) {
                const f32x4 v = acc[pb][hb];
                sum += clamp01(v[0]) * w2q[hb][0];
                sum += clamp01(v[1]) * w2q[hb][1];
                sum += clamp01(v[2]) * w2q[hb][2];
                sum += clamp01(v[3]) * w2q[hb][3];
            }
            PART[nq * 4 + q][pb * 16 + cl] = sum;
        }
        __syncthreads();   // B3: PART visible

        if (tid < 64) {
            float z = bias2;
            #pragma unroll
            for (int i = 0; i < 16; ++i) z += PART[i][tid];
            out[base + tid] = 1.f / (1.f + __expf(-z));
        }
        // hazards (2-barrier): A0n write -> next-tile L0 read crosses B2+B3;
        // A0c read -> its rewrite (next tile's staging) crosses B2+B3;
        // H0 read (L1) -> next-tile H0 write crosses B3; PART out-read ->
        // next-tile PART write crosses B2.
    }
}

extern "C" void kernel_launch(void* const* d_in, const int* in_sizes, int n_in,
                              void* d_out, int out_size, void* d_ws, size_t ws_size,
                              hipStream_t stream) {
    const float* x   = (const float*)d_in[0];
    const float* emb = (const float*)d_in[1];
    const float* emt = (const float*)d_in[2];
    const float* W0  = (const float*)d_in[3];
    const float* b0  = (const float*)d_in[4];
    const float* W1  = (const float*)d_in[5];
    const float* b1  = (const float*)d_in[6];
    const float* W2  = (const float*)d_in[7];
    const float* b2  = (const float*)d_in[8];
    mlp_fused<<<NBLOCKS, 256, 0, stream>>>(x, emb, emt, W0, b0, W1, b1, W2, b2,
                                           (float*)d_out);
}